// Round 3
// baseline (13292.596 us; speedup 1.0000x reference)
//
#include <hip/hip_runtime.h>

// 2-layer LSTM (B=32, T=512, D=H=1024), persistent kernel on MI355X.
// Blocks 0..127 = layer 0, 128..255 = layer 1 (pipelined, lags >=1 step).
// Block owns 8 h-columns -> 32 gate rows {f,i,o,cg}x8. Weights bf16 in LDS
// (128KB, XOR-swizzled). 4 waves = 4 K-chunks: waves 0,1 = input part (x/h0),
// waves 2,3 = recurrent part (h[t-1], the serial dependency).
// Cross-block sync: per-block flag arrays in ws + agent-scope fences
// (__threadfence; __hip_atomic_thread_fence does not exist in this ROCm).
// 145KB LDS/block -> 1 block/CU -> all 256 blocks co-resident (no deadlock).

#define BB 32
#define TT 512
#define HH 1024
#define NBLK 128
#define RINGM 7  // h0 ring = 8 slots

typedef float f32x4 __attribute__((ext_vector_type(4)));
typedef __bf16 bf16x8 __attribute__((ext_vector_type(8)));
typedef __bf16 bf16x4 __attribute__((ext_vector_type(4)));

// ws layout (bytes)
#define H0R_OFF 0            // [8][32][1024] bf16 = 512K
#define H1R_OFF (512*1024)   // [2][32][1024] bf16 = 128K
#define F0_OFF  (640*1024)   // [512][128] int = 256K
#define F1_OFF  (896*1024)   // [512][128] int = 256K
#define XBF_OFF (1152*1024)  // optional [512][32][1024] bf16 = 32M
#define WS_NEED_XBF ((size_t)(1152*1024) + (size_t)33554432)

__device__ __forceinline__ float sigm(float x){ return 1.f/(1.f+__expf(-x)); }
__device__ __forceinline__ float tanh_s(float x){
  float a = fminf(fabsf(x), 20.f);
  float e = __expf(2.f*a);
  float r = (e-1.f)/(e+1.f);
  return x < 0.f ? -r : r;
}
__device__ __forceinline__ void spin1(const int* p){
  while (__hip_atomic_load(p, __ATOMIC_RELAXED, __HIP_MEMORY_SCOPE_AGENT) == 0)
    __builtin_amdgcn_s_sleep(2);
}

__global__ __launch_bounds__(256) void xconv_kernel(const float* __restrict__ x,
                                                    __bf16* __restrict__ xbf){
  int i = blockIdx.x*256 + threadIdx.x;     // one float4 per thread
  int flat = i << 2;
  int b = flat >> 19, t = (flat >> 10) & (TT-1), d = flat & (HH-1);
  float4 v = *(const float4*)(x + flat);
  bf16x4 o;
  o[0]=(__bf16)v.x; o[1]=(__bf16)v.y; o[2]=(__bf16)v.z; o[3]=(__bf16)v.w;
  *(bf16x4*)(xbf + ((t*BB + b) << 10) + d) = o;
}

__global__ __launch_bounds__(256, 1) void lstm2(
    const float* __restrict__ x, const int* __restrict__ l32,
    const float* __restrict__ wih0, const float* __restrict__ whh0, const float* __restrict__ b0,
    const float* __restrict__ wih1, const float* __restrict__ whh1, const float* __restrict__ b1,
    float* __restrict__ out, char* __restrict__ ws, int use_xbf)
{
  extern __shared__ char smem[];
  float* redf = (float*)(smem + 131072);      // [4][32][33] f32 partials
  const int tid = threadIdx.x, bid = blockIdx.x;
  const int layer = bid >> 7, lb = bid & (NBLK-1), c0 = lb*8;
  const float* wih  = layer ? wih1 : wih0;
  const float* whh  = layer ? whh1 : whh0;
  const float* bias = layer ? b1 : b0;
  __bf16* h0r = (__bf16*)(ws + H0R_OFF);
  __bf16* h1r = (__bf16*)(ws + H1R_OFF);
  int* f0 = (int*)(ws + F0_OFF);
  int* f1 = (int*)(ws + F1_OFF);
  const __bf16* xbf = (const __bf16*)(ws + XBF_OFF);

  // ---- weights -> LDS bf16, XOR-swizzled (row m, byte (2k)^((m&7)<<4)) ----
  for (int idx = tid; idx < 32*1024; idx += 256){
    int m = idx >> 10, k = idx & (HH-1);
    int gr = (m >> 3)*HH + c0 + (m & 7);      // gate row: m/8 = gate {f,i,o,cg}
    int off = m*2048 + ((k*2) ^ ((m & 7) << 4));
    *(__bf16*)(smem + off)         = (__bf16)wih[(size_t)gr*HH + k];
    *(__bf16*)(smem + 65536 + off) = (__bf16)whh[(size_t)gr*HH + k];
  }

  // ---- lengths: detect int32 vs int64 (little-endian low word) ----
  int odd = 0;
#pragma unroll
  for (int i = 1; i < 32; i += 2) odd |= l32[i];
  const int eb = tid >> 3, ec = tid & 7, cgl = c0 + ec;
  const int mylen = odd ? l32[eb] : l32[2*eb];
  float bias_r[4];
#pragma unroll
  for (int g = 0; g < 4; ++g) bias_r[g] = bias[g*HH + cgl];
  float c_st = 0.f, h_st = 0.f;

  const int lane = tid & 63, wid = tid >> 6;
  const int part = wid >> 1;                  // 0 = input part, 1 = recurrent part
  const int kch  = wid & 1;                   // K-chunk within part (512 each)
  const int col16 = lane & 15, kgrp = lane >> 4;
  const int axor = (col16 & 7) << 4;
  const char* wbase = (const char*)smem + part*65536 + col16*2048 + kch*1024;
  const int j = tid & 127;                    // spin slot

  __syncthreads();                            // weights visible

  for (int t = 0; t < TT; ++t){
    // ---- dependency waits (recurrent-part waves only, except L1 input) ----
    if (layer == 0){
      if (part == 1){
        if (t > 0)  spin1(f0 + (t-1)*NBLK + j);   // peers' h0[t-1]
        if (t >= 8) spin1(f1 + (t-8)*NBLK + j);   // ring backpressure
        __threadfence();                          // acquire
      }
    } else {
      if (part == 0){
        spin1(f0 + t*NBLK + j);                   // h0[t] ready
      } else if (t > 0){
        spin1(f1 + (t-1)*NBLK + j);               // peers' h1[t-1]
      }
      __threadfence();                            // acquire
    }

    // ---- B source for this wave ----
    const __bf16* bsrc = nullptr;
    const float*  fsrc = nullptr;
    if (part == 0){
      if (layer)        bsrc = h0r + ((t & RINGM) << 15);
      else if (use_xbf) bsrc = xbf + (t << 15);
      else              fsrc = x + (t << 10);
    } else if (t > 0){
      bsrc = layer ? (h1r + (((t-1) & 1) << 15))
                   : (h0r + (((t-1) & RINGM) << 15));
    }

    // ---- MFMA: 32 gate rows x 32 batch, this wave's K-chunk of 512 ----
    f32x4 acc00={0,0,0,0}, acc01={0,0,0,0}, acc10={0,0,0,0}, acc11={0,0,0,0};
    const int kbase = kch*512 + kgrp*8;
    if (bsrc){
      const __bf16* p0 = bsrc + (col16 << 10) + kbase;
      const __bf16* p1 = bsrc + ((16+col16) << 10) + kbase;
#pragma unroll 4
      for (int kb = 0; kb < 16; ++kb){
        bf16x8 bv0 = *(const bf16x8*)(p0 + kb*32);
        bf16x8 bv1 = *(const bf16x8*)(p1 + kb*32);
        int ao = (kb*64 + kgrp*16) ^ axor;
        bf16x8 a0 = *(const bf16x8*)(wbase + ao);
        bf16x8 a1 = *(const bf16x8*)(wbase + 32768 + ao);
        acc00 = __builtin_amdgcn_mfma_f32_16x16x32_bf16(a0, bv0, acc00, 0,0,0);
        acc01 = __builtin_amdgcn_mfma_f32_16x16x32_bf16(a0, bv1, acc01, 0,0,0);
        acc10 = __builtin_amdgcn_mfma_f32_16x16x32_bf16(a1, bv0, acc10, 0,0,0);
        acc11 = __builtin_amdgcn_mfma_f32_16x16x32_bf16(a1, bv1, acc11, 0,0,0);
      }
    } else if (fsrc){
      const float* p0 = fsrc + ((size_t)col16 << 19) + kbase;
      const float* p1 = fsrc + ((size_t)(16+col16) << 19) + kbase;
#pragma unroll 4
      for (int kb = 0; kb < 16; ++kb){
        float4 u0a = *(const float4*)(p0 + kb*32), u0b = *(const float4*)(p0 + kb*32 + 4);
        float4 u1a = *(const float4*)(p1 + kb*32), u1b = *(const float4*)(p1 + kb*32 + 4);
        bf16x8 bv0, bv1;
        bv0[0]=(__bf16)u0a.x; bv0[1]=(__bf16)u0a.y; bv0[2]=(__bf16)u0a.z; bv0[3]=(__bf16)u0a.w;
        bv0[4]=(__bf16)u0b.x; bv0[5]=(__bf16)u0b.y; bv0[6]=(__bf16)u0b.z; bv0[7]=(__bf16)u0b.w;
        bv1[0]=(__bf16)u1a.x; bv1[1]=(__bf16)u1a.y; bv1[2]=(__bf16)u1a.z; bv1[3]=(__bf16)u1a.w;
        bv1[4]=(__bf16)u1b.x; bv1[5]=(__bf16)u1b.y; bv1[6]=(__bf16)u1b.z; bv1[7]=(__bf16)u1b.w;
        int ao = (kb*64 + kgrp*16) ^ axor;
        bf16x8 a0 = *(const bf16x8*)(wbase + ao);
        bf16x8 a1 = *(const bf16x8*)(wbase + 32768 + ao);
        acc00 = __builtin_amdgcn_mfma_f32_16x16x32_bf16(a0, bv0, acc00, 0,0,0);
        acc01 = __builtin_amdgcn_mfma_f32_16x16x32_bf16(a0, bv1, acc01, 0,0,0);
        acc10 = __builtin_amdgcn_mfma_f32_16x16x32_bf16(a1, bv0, acc10, 0,0,0);
        acc11 = __builtin_amdgcn_mfma_f32_16x16x32_bf16(a1, bv1, acc11, 0,0,0);
      }
    }

    // ---- partials -> LDS: redf[wid][m][33], m = mt*16 + kgrp*4 + r ----
#pragma unroll
    for (int r = 0; r < 4; ++r){
      int m0 = kgrp*4 + r;
      redf[wid*1056 + m0*33 + col16]           = acc00[r];
      redf[wid*1056 + m0*33 + 16 + col16]      = acc01[r];
      redf[wid*1056 + (m0+16)*33 + col16]      = acc10[r];
      redf[wid*1056 + (m0+16)*33 + 16 + col16] = acc11[r];
    }
    __syncthreads();

    // ---- pointwise LSTM update: thread = (batch eb, col ec) ----
    float vv[4];
#pragma unroll
    for (int g = 0; g < 4; ++g){
      int mi = (g*8 + ec)*33 + eb;
      vv[g] = redf[mi] + redf[1056 + mi] + redf[2112 + mi] + redf[3168 + mi] + bias_r[g];
    }
    float fg = sigm(vv[0]), ig = sigm(vv[1]), og = sigm(vv[2]), gg = tanh_s(vv[3]);
    float cn = fg*c_st + ig*gg;
    float hn = og*tanh_s(cn);
    if (t < mylen){ c_st = cn; h_st = hn; }    // hold semantics for t >= len
    __bf16 hb = (__bf16)h_st;
    if (layer == 0){
      h0r[((t & RINGM) << 15) + (eb << 10) + cgl] = hb;
    } else {
      h1r[((t & 1) << 15) + (eb << 10) + cgl] = hb;
      out[((size_t)(eb*TT + t) << 10) + cgl] = h_st;   // out1[b][t][h]
    }
    __syncthreads();                           // all threads' h stores issued
    if (tid == 0){
      __threadfence();                         // release: h visible before flag
      __hip_atomic_store((layer ? f1 : f0) + t*NBLK + lb, 1,
                         __ATOMIC_RELAXED, __HIP_MEMORY_SCOPE_AGENT);
    }
  }

  // finals: out1 | c[2][B][H] | h[2][B][H]
  const size_t OFFC = (size_t)BB*TT*HH;
  out[OFFC + (layer << 15) + (eb << 10) + cgl] = c_st;
  out[OFFC + ((2 + layer) << 15) + (eb << 10) + cgl] = h_st;
}

extern "C" void kernel_launch(void* const* d_in, const int* in_sizes, int n_in,
                              void* d_out, int out_size, void* d_ws, size_t ws_size,
                              hipStream_t stream) {
  const float* x    = (const float*)d_in[0];
  const int*   lens = (const int*)d_in[1];
  const float* wih0 = (const float*)d_in[2];
  const float* whh0 = (const float*)d_in[3];
  const float* b0   = (const float*)d_in[4];
  const float* wih1 = (const float*)d_in[5];
  const float* whh1 = (const float*)d_in[6];
  const float* b1   = (const float*)d_in[7];
  float* out = (float*)d_out;
  char* ws = (char*)d_ws;

  const int use_xbf = (ws_size >= WS_NEED_XBF) ? 1 : 0;

  // zero the flag arrays (re-poisoned to 0xAA before every timed call)
  (void)hipMemsetAsync(ws + F0_OFF, 0, 512*1024, stream);

  if (use_xbf)
    xconv_kernel<<<dim3(16384), dim3(256), 0, stream>>>(x, (__bf16*)(ws + XBF_OFF));

  const int lds_bytes = 131072 + 4*1056*4;   // weights + redf = 147968
  (void)hipFuncSetAttribute((const void*)lstm2,
                            hipFuncAttributeMaxDynamicSharedMemorySize, lds_bytes);
  lstm2<<<dim3(256), dim3(256), lds_bytes, stream>>>(
      x, lens, wih0, whh0, b0, wih1, whh1, b1, out, ws, use_xbf);
}

// Round 5
// 5805.270 us; speedup vs baseline: 2.2897x; 2.2897x over previous
//
#include <hip/hip_runtime.h>

// 2-layer LSTM (B=32, T=512, D=H=1024), persistent dataflow kernel, MI355X.
// Blocks 0..127 = layer 0, 128..255 = layer 1 (chases L0 via dataflow).
// Sync redesign vs round 3 (26us/step, fence-bound): NO __threadfence
// (wbl2/inv full-L2 ops were the bottleneck). h transported via MALL-coherent
// sc0 sc1 stores/loads; ordering = vmcnt(0) ack + monotonic per-producer flag
// (fl[lb] = t+1, agent-scope atomic). Full-T h buffers -> no backpressure,
// pure forward dataflow, deadlock-free. redf transposed ([wid][col][36]) to
// kill the 33-stride bank conflicts (1.34e8/dispatch in round 3).

#define BB 32
#define TT 512
#define HH 1024
#define NBLK 128

typedef float f32x4 __attribute__((ext_vector_type(4)));
typedef __bf16 bf16x8 __attribute__((ext_vector_type(8)));
typedef unsigned int u32x4 __attribute__((ext_vector_type(4)));

// ws layout (bytes); round 0 proved ws_size >= ~67.25MB
#define H0_OFF  0            // [512][32][1024] bf16 = 32MB
#define H1_OFF  33554432     // [512][32][1024] bf16 = 32MB
#define FL0_OFF 67108864     // int[128] monotonic (t+1)
#define FL1_OFF (67108864 + 512)

#define LD16(d, a) asm volatile("global_load_dwordx4 %0, %1, off sc0 sc1" \
                                : "=v"(d) : "v"(a) : "memory")
#define ST16(a, v) asm volatile("global_store_dwordx4 %0, %1, off sc0 sc1" \
                                :: "v"(a), "v"(v) : "memory")

__device__ __forceinline__ float sigm(float x){ return 1.f/(1.f+__expf(-x)); }
__device__ __forceinline__ float tanh_s(float x){
  float a = fminf(fabsf(x), 20.f);
  float e = __expf(2.f*a);
  float r = (e-1.f)/(e+1.f);
  return x < 0.f ? -r : r;
}

// all 64 lanes poll 128 monotonic flags (2 each) until >= need
__device__ __forceinline__ void waitflag(const int* fl, int lane, int need){
  const int* p = fl + 2*lane;
  for (;;){
    int a = __hip_atomic_load(p,   __ATOMIC_RELAXED, __HIP_MEMORY_SCOPE_AGENT);
    int b = __hip_atomic_load(p+1, __ATOMIC_RELAXED, __HIP_MEMORY_SCOPE_AGENT);
    if (!__any((a < need) | (b < need))) return;
    __builtin_amdgcn_s_sleep(1);
  }
}

__global__ __launch_bounds__(256, 1) void lstm2(
    const float* __restrict__ x, const int* __restrict__ l32,
    const float* __restrict__ wih0, const float* __restrict__ whh0, const float* __restrict__ b0,
    const float* __restrict__ wih1, const float* __restrict__ whh1, const float* __restrict__ b1,
    float* __restrict__ out, char* __restrict__ ws)
{
  extern __shared__ char smem[];
  float* redf = (float*)(smem + 131072);        // [4][32][36] f32, transposed reduce
  __bf16* hstage = (__bf16*)(smem + 149504);    // [32][8]
  const int tid = threadIdx.x, bid = blockIdx.x;
  const int layer = bid >> 7, lb = bid & (NBLK-1), c0 = lb*8;
  const float* wih  = layer ? wih1 : wih0;
  const float* whh  = layer ? whh1 : whh0;
  const float* bias = layer ? b1 : b0;
  __bf16* h0b = (__bf16*)(ws + H0_OFF);
  __bf16* h1b = (__bf16*)(ws + H1_OFF);
  int* fl0 = (int*)(ws + FL0_OFF);
  int* fl1 = (int*)(ws + FL1_OFF);

  // ---- weights -> LDS bf16, XOR-swizzle byte ^= (m&15)<<4 ----
  for (int idx = tid; idx < 32*1024; idx += 256){
    int m = idx >> 10, k = idx & (HH-1);
    int gr = (m >> 3)*HH + c0 + (m & 7);        // gates {f,i,o,cg} x 8 cols
    int off = m*2048 + ((k*2) ^ ((m & 15) << 4));
    *(__bf16*)(smem + off)         = (__bf16)wih[(size_t)gr*HH + k];
    *(__bf16*)(smem + 65536 + off) = (__bf16)whh[(size_t)gr*HH + k];
  }

  // lengths: int32 vs int64 detect (odd words all-zero => int64)
  int odd = 0;
#pragma unroll
  for (int i = 1; i < 32; i += 2) odd |= l32[i];
  const int eb = tid >> 3, ec = tid & 7, cgl = c0 + ec;
  const int mylen = odd ? l32[eb] : l32[2*eb];
  float bias_r[4];
#pragma unroll
  for (int g = 0; g < 4; ++g) bias_r[g] = bias[g*HH + cgl];
  float c_st = 0.f, h_st = 0.f;

  const int lane = tid & 63, wid = tid >> 6;
  const int part = wid >> 1;                    // 0: input part, 1: recurrent part
  const int kch  = wid & 1;                     // K-chunk of 512
  const int col16 = lane & 15, kgrp = lane >> 4;
  const int axor = col16 << 4;
  const char* wbase = (const char*)smem + part*65536 + col16*2048 + kch*1024;
  float* wr = redf + wid*1152;
  const int kbase = kch*512 + kgrp*8;

  __syncthreads();                              // weights visible

  for (int t = 0; t < TT; ++t){
    f32x4 acc00={0,0,0,0}, acc01={0,0,0,0}, acc10={0,0,0,0}, acc11={0,0,0,0};

    // ---- select B source; poll producer flags if cross-block data ----
    const __bf16* bsrc = nullptr;
    const float*  fsrc = nullptr;
    const int* fl = nullptr; int need = 0;
    if (layer == 0){
      if (part == 0) fsrc = x + (t << 10);
      else if (t > 0){ bsrc = h0b + ((size_t)(t-1) << 15); fl = fl0; need = t; }
    } else {
      if (part == 0){ bsrc = h0b + ((size_t)t << 15); fl = fl0; need = t+1; }
      else if (t > 0){ bsrc = h1b + ((size_t)(t-1) << 15); fl = fl1; need = t; }
    }
    if (fl) waitflag(fl, lane, need);

    if (bsrc){
      // bulk coherent load: 2 rows x 16 chunks of 16B, one vmcnt drain
      const char* pa = (const char*)(bsrc + col16*HH + kbase);
      const char* pb = (const char*)(bsrc + (16+col16)*HH + kbase);
      u32x4 ra[16], rb[16];
#pragma unroll
      for (int u = 0; u < 16; ++u){ LD16(ra[u], pa + u*64); LD16(rb[u], pb + u*64); }
      asm volatile("s_waitcnt vmcnt(0)" ::: "memory");
      __builtin_amdgcn_sched_barrier(0);
#pragma unroll
      for (int u = 0; u < 16; ++u){
        bf16x8 bv0 = __builtin_bit_cast(bf16x8, ra[u]);
        bf16x8 bv1 = __builtin_bit_cast(bf16x8, rb[u]);
        int ao = (u*64 + kgrp*16) ^ axor;
        bf16x8 a0 = *(const bf16x8*)(wbase + ao);
        bf16x8 a1 = *(const bf16x8*)(wbase + 32768 + ao);
        acc00 = __builtin_amdgcn_mfma_f32_16x16x32_bf16(a0, bv0, acc00, 0,0,0);
        acc01 = __builtin_amdgcn_mfma_f32_16x16x32_bf16(a0, bv1, acc01, 0,0,0);
        acc10 = __builtin_amdgcn_mfma_f32_16x16x32_bf16(a1, bv0, acc10, 0,0,0);
        acc11 = __builtin_amdgcn_mfma_f32_16x16x32_bf16(a1, bv1, acc11, 0,0,0);
      }
    } else if (fsrc){
      // L0 input part: plain cached fp32 x reads + cvt (off critical path)
      const float* p0 = fsrc + ((size_t)col16 << 19) + kbase;
      const float* p1 = fsrc + ((size_t)(16+col16) << 19) + kbase;
#pragma unroll 4
      for (int kb = 0; kb < 16; ++kb){
        float4 u0a = *(const float4*)(p0 + kb*32), u0b = *(const float4*)(p0 + kb*32 + 4);
        float4 u1a = *(const float4*)(p1 + kb*32), u1b = *(const float4*)(p1 + kb*32 + 4);
        bf16x8 bv0, bv1;
        bv0[0]=(__bf16)u0a.x; bv0[1]=(__bf16)u0a.y; bv0[2]=(__bf16)u0a.z; bv0[3]=(__bf16)u0a.w;
        bv0[4]=(__bf16)u0b.x; bv0[5]=(__bf16)u0b.y; bv0[6]=(__bf16)u0b.z; bv0[7]=(__bf16)u0b.w;
        bv1[0]=(__bf16)u1a.x; bv1[1]=(__bf16)u1a.y; bv1[2]=(__bf16)u1a.z; bv1[3]=(__bf16)u1a.w;
        bv1[4]=(__bf16)u1b.x; bv1[5]=(__bf16)u1b.y; bv1[6]=(__bf16)u1b.z; bv1[7]=(__bf16)u1b.w;
        int ao = (kb*64 + kgrp*16) ^ axor;
        bf16x8 a0 = *(const bf16x8*)(wbase + ao);
        bf16x8 a1 = *(const bf16x8*)(wbase + 32768 + ao);
        acc00 = __builtin_amdgcn_mfma_f32_16x16x32_bf16(a0, bv0, acc00, 0,0,0);
        acc01 = __builtin_amdgcn_mfma_f32_16x16x32_bf16(a0, bv1, acc01, 0,0,0);
        acc10 = __builtin_amdgcn_mfma_f32_16x16x32_bf16(a1, bv0, acc10, 0,0,0);
        acc11 = __builtin_amdgcn_mfma_f32_16x16x32_bf16(a1, bv1, acc11, 0,0,0);
      }
    }

    // ---- partials -> LDS, transposed: redf[wid][col][m], b128 stores ----
    *(f32x4*)(wr + col16*36 + kgrp*4)           = acc00;
    *(f32x4*)(wr + (16+col16)*36 + kgrp*4)      = acc01;
    *(f32x4*)(wr + col16*36 + 16 + kgrp*4)      = acc10;
    *(f32x4*)(wr + (16+col16)*36 + 16 + kgrp*4) = acc11;
    __syncthreads();

    // ---- pointwise LSTM update: thread = (batch eb, col ec) ----
    float vv[4];
#pragma unroll
    for (int g = 0; g < 4; ++g){
      int mi = eb*36 + g*8 + ec;
      vv[g] = redf[mi] + redf[1152+mi] + redf[2304+mi] + redf[3456+mi] + bias_r[g];
    }
    float fg = sigm(vv[0]), ig = sigm(vv[1]), og = sigm(vv[2]), gg = tanh_s(vv[3]);
    float cn = fg*c_st + ig*gg;
    float hn = og*tanh_s(cn);
    if (t < mylen){ c_st = cn; h_st = hn; }     // hold semantics for t >= len
    hstage[eb*8 + ec] = (__bf16)h_st;
    if (layer) out[((size_t)(eb*TT + t) << 10) + cgl] = h_st;  // plain cached
    __syncthreads();

    // ---- publish: wave0 stores the 32x8 h-slice coherent, then flag ----
    if (wid == 0){
      __bf16* hb = (layer ? h1b : h0b) + ((size_t)t << 15) + c0;
      if (lane < 32){
        u32x4 hv = *(const u32x4*)(hstage + lane*8);
        ST16(hb + (size_t)lane*HH, hv);
      }
      asm volatile("s_waitcnt vmcnt(0)" ::: "memory");   // acked at coherent point
      if (lane == 0)
        __hip_atomic_store((layer ? fl1 : fl0) + lb, t+1,
                           __ATOMIC_RELAXED, __HIP_MEMORY_SCOPE_AGENT);
    }
  }

  // finals: out1 | c[2][B][H] | h[2][B][H]
  const size_t OFFC = (size_t)BB*TT*HH;
  out[OFFC + (layer << 15) + (eb << 10) + cgl] = c_st;
  out[OFFC + ((2 + layer) << 15) + (eb << 10) + cgl] = h_st;
}

extern "C" void kernel_launch(void* const* d_in, const int* in_sizes, int n_in,
                              void* d_out, int out_size, void* d_ws, size_t ws_size,
                              hipStream_t stream) {
  const float* x    = (const float*)d_in[0];
  const int*   lens = (const int*)d_in[1];
  const float* wih0 = (const float*)d_in[2];
  const float* whh0 = (const float*)d_in[3];
  const float* b0   = (const float*)d_in[4];
  const float* wih1 = (const float*)d_in[5];
  const float* whh1 = (const float*)d_in[6];
  const float* b1   = (const float*)d_in[7];
  float* out = (float*)d_out;
  char* ws = (char*)d_ws;

  // reset monotonic flags (ws is re-poisoned 0xAA before every timed call)
  (void)hipMemsetAsync(ws + FL0_OFF, 0, 1024, stream);

  const int lds_bytes = 131072 + 4*1152*4 + 512;   // weights + redf + hstage = 150016
  (void)hipFuncSetAttribute((const void*)lstm2,
                            hipFuncAttributeMaxDynamicSharedMemorySize, lds_bytes);
  lstm2<<<dim3(256), dim3(256), lds_bytes, stream>>>(
      x, lens, wih0, whh0, b0, wih1, whh1, b1, out, ws);
}

// Round 6
// 5083.771 us; speedup vs baseline: 2.6147x; 1.1419x over previous
//
#include <hip/hip_runtime.h>

// 2-layer LSTM (B=32, T=512, D=H=1024), persistent dataflow kernel, MI355X.
// Round-6 sync redesign vs round 5 (11.3us/step):
//  - per-step single counter cnt[t] (atomicAdd once per producer block);
//    consumers poll ONE address coalesced (round 5 polled 128 flag addresses
//    per-lane atomically -> uncoalesced MALL storm).
//  - h/B reads are PLAIN CACHED loads (L2-shared per XCD). Safe because each
//    h slice address is written exactly once per dispatch, readers only touch
//    it after the counter trips, and the dispatch-start acquire invalidated
//    all caches. Producers still write-through (sc0 sc1) + vmcnt(0) ack.
//  - 512B guard gap between h time-slices (defense vs adjacent-line fills).
//  - h1 = ring-4 (safe: a block reaches step t+1 only after cnt1[t]==128,
//    i.e. every peer has already consumed slot t-1). h0 stays full-T (L1 lag
//    vs L0 is unbounded). x pre-converted to bf16 [t][b][d] by xconv.
// Blocks 0..127 = layer 0, 128..255 = layer 1. Block owns 8 h-cols ->
// 32 gate rows {f,i,o,cg}x8; weights bf16 in LDS, XOR-swizzled. 4 waves =
// {input part, recurrent part} x {K-chunk 0,1}. 150KB LDS -> 1 block/CU.

#define BB 32
#define TT 512
#define HH 1024
#define NBLK 128
#define TSTR 66048   // h slice stride: 64KB data + 512B guard

typedef float f32x4 __attribute__((ext_vector_type(4)));
typedef __bf16 bf16x8 __attribute__((ext_vector_type(8)));
typedef __bf16 bf16x4 __attribute__((ext_vector_type(4)));
typedef unsigned int u32x4 __attribute__((ext_vector_type(4)));

// ws layout (bytes); rounds 0/3/5 proved ws_size >= ~67.2MB
#define H0_OFF   0                         // 512 * TSTR = 33,816,576
#define H1R_OFF  33816576                  // 4 * TSTR   = 264,192
#define CNT_OFF  34080768                  // cnt0[512] | cnt1[512] ints = 4KB
#define XBF_OFF  34084864                  // [512][32][1024] bf16 = 32MB (end 64.5MB)

// plain cached 16B load (L2/L1 allowed)
#define LDC16(d, a) asm volatile("global_load_dwordx4 %0, %1, off" \
                                 : "=v"(d) : "v"(a) : "memory")
// write-through coherent 16B store
#define ST16(a, v) asm volatile("global_store_dwordx4 %0, %1, off sc0 sc1" \
                                :: "v"(a), "v"(v) : "memory")

__device__ __forceinline__ float sigm(float x){ return 1.f/(1.f+__expf(-x)); }
__device__ __forceinline__ float tanh_s(float x){
  float a = fminf(fabsf(x), 20.f);
  float e = __expf(2.f*a);
  float r = (e-1.f)/(e+1.f);
  return x < 0.f ? -r : r;
}
// coherent (MALL) scalar load, all lanes same addr -> one transaction
__device__ __forceinline__ int ld_coh(const int* p){
  int v;
  asm volatile("global_load_dword %0, %1, off sc0 sc1\n\ts_waitcnt vmcnt(0)"
               : "=v"(v) : "v"(p) : "memory");
  return v;
}
__device__ __forceinline__ void poll128(const int* p){
  while (ld_coh(p) < NBLK) __builtin_amdgcn_s_sleep(1);
}

__global__ __launch_bounds__(256) void xconv_kernel(const float* __restrict__ x,
                                                    __bf16* __restrict__ xbf){
  int i = blockIdx.x*256 + threadIdx.x;     // one float4 per thread
  int flat = i << 2;
  int b = flat >> 19, t = (flat >> 10) & (TT-1), d = flat & (HH-1);
  float4 v = *(const float4*)(x + flat);
  bf16x4 o;
  o[0]=(__bf16)v.x; o[1]=(__bf16)v.y; o[2]=(__bf16)v.z; o[3]=(__bf16)v.w;
  *(bf16x4*)(xbf + ((t*BB + b) << 10) + d) = o;   // [t][b][d], plain stores
}

__global__ __launch_bounds__(256, 1) void lstm2(
    const int* __restrict__ l32,
    const float* __restrict__ wih0, const float* __restrict__ whh0, const float* __restrict__ b0,
    const float* __restrict__ wih1, const float* __restrict__ whh1, const float* __restrict__ b1,
    float* __restrict__ out, char* __restrict__ ws)
{
  extern __shared__ char smem[];
  float* redf = (float*)(smem + 131072);        // [4][32][36] f32 transposed reduce
  __bf16* hstage = (__bf16*)(smem + 149504);    // [32][8]
  const int tid = threadIdx.x, bid = blockIdx.x;
  const int layer = bid >> 7, lb = bid & (NBLK-1), c0 = lb*8;
  const float* wih  = layer ? wih1 : wih0;
  const float* whh  = layer ? whh1 : whh0;
  const float* bias = layer ? b1 : b0;
  char* h0 = ws + H0_OFF;
  char* h1r = ws + H1R_OFF;
  int* cnt0 = (int*)(ws + CNT_OFF);
  int* cnt1 = cnt0 + 512;
  const char* xb = ws + XBF_OFF;

  // ---- weights -> LDS bf16, XOR-swizzle byte ^= (m&15)<<4 ----
  for (int idx = tid; idx < 32*1024; idx += 256){
    int m = idx >> 10, k = idx & (HH-1);
    int gr = (m >> 3)*HH + c0 + (m & 7);        // gates {f,i,o,cg} x 8 cols
    int off = m*2048 + ((k*2) ^ ((m & 15) << 4));
    *(__bf16*)(smem + off)         = (__bf16)wih[(size_t)gr*HH + k];
    *(__bf16*)(smem + 65536 + off) = (__bf16)whh[(size_t)gr*HH + k];
  }

  // lengths: int32 vs int64 detect (odd words all-zero => int64)
  int odd = 0;
#pragma unroll
  for (int i = 1; i < 32; i += 2) odd |= l32[i];
  const int eb = tid >> 3, ec = tid & 7, cgl = c0 + ec;
  const int mylen = odd ? l32[eb] : l32[2*eb];
  float bias_r[4];
#pragma unroll
  for (int g = 0; g < 4; ++g) bias_r[g] = bias[g*HH + cgl];
  float c_st = 0.f, h_st = 0.f;

  const int lane = tid & 63, wid = tid >> 6;
  const int part = wid >> 1;                    // 0: input part, 1: recurrent part
  const int kch  = wid & 1;                     // K-chunk of 512
  const int col16 = lane & 15, kgrp = lane >> 4;
  const int axor = col16 << 4;
  const char* wbase = (const char*)smem + part*65536 + col16*2048 + kch*1024;
  float* wr = redf + wid*1152;
  const int kbase = kch*512 + kgrp*8;

  __syncthreads();                              // weights visible

  for (int t = 0; t < TT; ++t){
    f32x4 acc00={0,0,0,0}, acc01={0,0,0,0}, acc10={0,0,0,0}, acc11={0,0,0,0};

    // ---- select B source + producer counter to wait on ----
    const char* sb = nullptr;
    const int* pollp = nullptr;
    if (layer == 0){
      if (part == 0) sb = xb + ((size_t)t << 16);
      else if (t > 0){ sb = h0 + (size_t)(t-1)*TSTR; pollp = cnt0 + (t-1); }
    } else {
      if (part == 0){ sb = h0 + (size_t)t*TSTR; pollp = cnt0 + t; }
      else if (t > 0){ sb = h1r + (size_t)((t-1)&3)*TSTR; pollp = cnt1 + (t-1); }
    }
    if (pollp) poll128(pollp);                  // one coalesced load per poll

    if (sb){
      const char* pa = sb + col16*2048 + kbase*2;
      const char* pb = sb + (16+col16)*2048 + kbase*2;
      u32x4 ra[16], rb[16];
#pragma unroll
      for (int u = 0; u < 16; ++u){ LDC16(ra[u], pa + u*64); LDC16(rb[u], pb + u*64); }
      asm volatile("s_waitcnt vmcnt(0)" ::: "memory");
      __builtin_amdgcn_sched_barrier(0);
#pragma unroll
      for (int u = 0; u < 16; ++u){
        bf16x8 bv0 = __builtin_bit_cast(bf16x8, ra[u]);
        bf16x8 bv1 = __builtin_bit_cast(bf16x8, rb[u]);
        int ao = (u*64 + kgrp*16) ^ axor;
        bf16x8 a0 = *(const bf16x8*)(wbase + ao);
        bf16x8 a1 = *(const bf16x8*)(wbase + 32768 + ao);
        acc00 = __builtin_amdgcn_mfma_f32_16x16x32_bf16(a0, bv0, acc00, 0,0,0);
        acc01 = __builtin_amdgcn_mfma_f32_16x16x32_bf16(a0, bv1, acc01, 0,0,0);
        acc10 = __builtin_amdgcn_mfma_f32_16x16x32_bf16(a1, bv0, acc10, 0,0,0);
        acc11 = __builtin_amdgcn_mfma_f32_16x16x32_bf16(a1, bv1, acc11, 0,0,0);
      }
    }

    // ---- partials -> LDS, transposed: redf[wid][col][m], b128 stores ----
    *(f32x4*)(wr + col16*36 + kgrp*4)           = acc00;
    *(f32x4*)(wr + (16+col16)*36 + kgrp*4)      = acc01;
    *(f32x4*)(wr + col16*36 + 16 + kgrp*4)      = acc10;
    *(f32x4*)(wr + (16+col16)*36 + 16 + kgrp*4) = acc11;
    __syncthreads();

    // ---- pointwise LSTM update: thread = (batch eb, col ec) ----
    float vv[4];
#pragma unroll
    for (int g = 0; g < 4; ++g){
      int mi = eb*36 + g*8 + ec;
      vv[g] = redf[mi] + redf[1152+mi] + redf[2304+mi] + redf[3456+mi] + bias_r[g];
    }
    float fg = sigm(vv[0]), ig = sigm(vv[1]), og = sigm(vv[2]), gg = tanh_s(vv[3]);
    float cn = fg*c_st + ig*gg;
    float hn = og*tanh_s(cn);
    if (t < mylen){ c_st = cn; h_st = hn; }     // hold semantics for t >= len
    hstage[eb*8 + ec] = (__bf16)h_st;
    if (layer) out[((size_t)(eb*TT + t) << 10) + cgl] = h_st;  // out1[b][t][h]
    __syncthreads();

    // ---- publish: wave0 writes 32x8 h-slice through to MALL, then count ----
    if (wid == 0){
      char* hb = (layer ? (h1r + (size_t)(t&3)*TSTR) : (h0 + (size_t)t*TSTR)) + c0*2;
      if (lane < 32){
        u32x4 hv = *(const u32x4*)(hstage + lane*8);
        ST16(hb + (size_t)lane*2048, hv);
      }
      asm volatile("s_waitcnt vmcnt(0)" ::: "memory");   // acked at coherent point
      if (lane == 0)
        __hip_atomic_fetch_add((layer ? cnt1 : cnt0) + t, 1,
                               __ATOMIC_RELAXED, __HIP_MEMORY_SCOPE_AGENT);
    }
  }

  // finals: out1 | c[2][B][H] | h[2][B][H]
  const size_t OFFC = (size_t)BB*TT*HH;
  out[OFFC + (layer << 15) + (eb << 10) + cgl] = c_st;
  out[OFFC + ((2 + layer) << 15) + (eb << 10) + cgl] = h_st;
}

extern "C" void kernel_launch(void* const* d_in, const int* in_sizes, int n_in,
                              void* d_out, int out_size, void* d_ws, size_t ws_size,
                              hipStream_t stream) {
  const float* x    = (const float*)d_in[0];
  const int*   lens = (const int*)d_in[1];
  const float* wih0 = (const float*)d_in[2];
  const float* whh0 = (const float*)d_in[3];
  const float* b0   = (const float*)d_in[4];
  const float* wih1 = (const float*)d_in[5];
  const float* whh1 = (const float*)d_in[6];
  const float* b1   = (const float*)d_in[7];
  float* out = (float*)d_out;
  char* ws = (char*)d_ws;

  // zero step counters (ws re-poisoned 0xAA before every timed call)
  (void)hipMemsetAsync(ws + CNT_OFF, 0, 4096, stream);
  // x -> bf16 [t][b][d] (visible to lstm2 via dispatch-boundary release/acquire)
  xconv_kernel<<<dim3(16384), dim3(256), 0, stream>>>(x, (__bf16*)(ws + XBF_OFF));

  const int lds_bytes = 131072 + 4*1152*4 + 512;   // weights + redf + hstage = 150016
  (void)hipFuncSetAttribute((const void*)lstm2,
                            hipFuncAttributeMaxDynamicSharedMemorySize, lds_bytes);
  lstm2<<<dim3(256), dim3(256), lds_bytes, stream>>>(
      lens, wih0, whh0, b0, wih1, whh1, b1, out, ws);
}